// Round 1
// baseline (57.902 us; speedup 1.0000x reference)
//
#include <hip/hip_runtime.h>
#include <math.h>

// DbrxRouter on MI355X:
//   logits = x[8192,6144] @ W^T[6144,16]; softmax; top-4; p=1 renorm.
//   Renorm cancels the softmax denominator -> only top-4 logits needed.
// Memory-bound: 201.3 MB of x at ~6.3 TB/s -> ~32 us floor.

constexpr int H       = 6144;
constexpr int E       = 16;
constexpr int TPB     = 256;       // 4 waves
constexpr int TOK_PB  = 16;        // tokens per block (2 wave-pairs x 8)
constexpr int T_TOTAL = 8192;

__global__ __launch_bounds__(TPB, 2)
void dbrx_router(const float* __restrict__ x,
                 const float* __restrict__ w,
                 float* __restrict__ out)
{
    __shared__ float lds[4][8][16];   // [wave][token][expert] partial logits

    const int tid   = threadIdx.x;
    const int wave  = tid >> 6;
    const int lane  = tid & 63;
    const int pair  = wave >> 1;      // which 8-token group
    const int hhalf = wave & 1;       // which H half this wave covers

    const int tok0 = blockIdx.x * TOK_PB + pair * 8;
    const float* xbase = x + (size_t)tok0 * H + hhalf * (H / 2) + lane * 4;
    const float* wbase = w + hhalf * (H / 2) + lane * 4;

    // acc[t*16+e]: per-lane partial logits for 8 tokens x 16 experts
    float acc[128];
    #pragma unroll
    for (int i = 0; i < 128; ++i) acc[i] = 0.f;

    // H loop: each iteration the wave covers 256 contiguous floats (float4/lane)
    #pragma unroll 2
    for (int i = 0; i < (H / 2) / 256; ++i) {
        float4 xv[8];
        #pragma unroll
        for (int t = 0; t < 8; ++t)
            xv[t] = *reinterpret_cast<const float4*>(xbase + (size_t)t * H + i * 256);

        #pragma unroll
        for (int eb = 0; eb < 2; ++eb) {      // experts in two blocks of 8
            float4 wv[8];
            #pragma unroll
            for (int e = 0; e < 8; ++e)
                wv[e] = *reinterpret_cast<const float4*>(wbase + (size_t)(eb * 8 + e) * H + i * 256);

            #pragma unroll
            for (int t = 0; t < 8; ++t) {
                #pragma unroll
                for (int e = 0; e < 8; ++e) {
                    float s = acc[t * 16 + eb * 8 + e];
                    s = fmaf(xv[t].x, wv[e].x, s);
                    s = fmaf(xv[t].y, wv[e].y, s);
                    s = fmaf(xv[t].z, wv[e].z, s);
                    s = fmaf(xv[t].w, wv[e].w, s);
                    acc[t * 16 + eb * 8 + e] = s;
                }
            }
        }
    }

    // Butterfly reduce-SCATTER across 64 lanes: 128 partials -> 2 fully
    // reduced logits per lane (252 adds vs 1536 for a full butterfly).
    // After step with mask m, lane keeps the half selected by its own bit.
    #pragma unroll
    for (int s = 0; s < 6; ++s) {
        const int m      = 32 >> s;
        const int half_n = 64 >> s;
        const bool hi    = (lane & m) != 0;
        #pragma unroll
        for (int i = 0; i < 64; ++i) {       // bounded by current half_n
            if (i >= half_n) break;
            float send = hi ? acc[i] : acc[i + half_n];
            float keep = hi ? acc[i + half_n] : acc[i];
            float recv = __shfl_xor(send, m, 64);
            acc[i] = keep + recv;
        }
    }
    // Lane now holds logits[t][e0], logits[t][e0+1] with:
    const int t_loc = (lane >> 3) & 7;
    const int e0    = (lane & 7) << 1;
    lds[wave][t_loc][e0]     = acc[0];
    lds[wave][t_loc][e0 + 1] = acc[1];
    __syncthreads();

    // Final phase: one thread per token combines the two H-halves,
    // does top-4 (strict > == lowest-index tie-break, matching np/jax),
    // and the normalized weights exp(l-lmax)/sum_top4.
    if (tid < TOK_PB) {
        const int p  = tid >> 3;
        const int tl = tid & 7;
        float lg[16];
        #pragma unroll
        for (int e = 0; e < 16; ++e)
            lg[e] = lds[2 * p][tl][e] + lds[2 * p + 1][tl][e];

        float topv[4];
        int   topi[4];
        #pragma unroll
        for (int k = 0; k < 4; ++k) {
            float m = lg[0]; int mi = 0;
            #pragma unroll
            for (int e = 1; e < 16; ++e)
                if (lg[e] > m) { m = lg[e]; mi = e; }
            topv[k] = m; topi[k] = mi;
            #pragma unroll
            for (int e = 0; e < 16; ++e)      // static-index mask-out (no scratch)
                if (e == mi) lg[e] = -INFINITY;
        }

        float ex[4]; float sum = 0.f;
        #pragma unroll
        for (int k = 0; k < 4; ++k) { ex[k] = __expf(topv[k] - topv[0]); sum += ex[k]; }
        const float inv = 1.0f / sum;

        const int tok = blockIdx.x * TOK_PB + tid;
        #pragma unroll
        for (int k = 0; k < 4; ++k) {
            out[(size_t)tok * 4 + k] = ex[k] * inv;                         // top_weights
            out[(size_t)T_TOTAL * 4 + (size_t)tok * 4 + k] = (float)topi[k]; // top_experts
        }
    }
}

extern "C" void kernel_launch(void* const* d_in, const int* in_sizes, int n_in,
                              void* d_out, int out_size, void* d_ws, size_t ws_size,
                              hipStream_t stream) {
    const float* x = (const float*)d_in[0];   // hidden_states [4,2048,6144] fp32
    const float* w = (const float*)d_in[1];   // router_weight [16,6144] fp32
    float* out     = (float*)d_out;           // [8192*4 weights][8192*4 expert ids]
    dbrx_router<<<T_TOTAL / TOK_PB, TPB, 0, stream>>>(x, w, out);
}